// Round 11
// baseline (54.620 us; speedup 1.0000x reference)
//
#include <hip/hip_runtime.h>

#define Bn 8
#define Nn 2048
#define Dn 128
#define OUTn 128

typedef __attribute__((ext_vector_type(8))) short bf16x8;     // MFMA A/B operand (8 bf16)
typedef __attribute__((ext_vector_type(8))) unsigned short ushort8;
typedef __attribute__((ext_vector_type(4))) float f32x4;      // MFMA C/D
typedef __attribute__((ext_vector_type(4))) int int4v;
typedef __attribute__((ext_vector_type(4))) unsigned int uint4v;
typedef __attribute__((ext_vector_type(4))) float float4v;

__device__ __forceinline__ unsigned short f2bf(float f) {
  unsigned int u = __builtin_bit_cast(unsigned int, f);
  u += 0x7FFFu + ((u >> 16) & 1u);   // round-to-nearest-even
  return (unsigned short)(u >> 16);
}

// ---------------- prep: transpose input + transpose W ----------------
__global__ __launch_bounds__(256) void gcn_prep(const float* __restrict__ in,
                                                const float* __restrict__ W,
                                                unsigned short* __restrict__ inT,
                                                unsigned short* __restrict__ WT) {
  const int tid = threadIdx.x;
  if (blockIdx.x >= 256) {
    int gid = (blockIdx.x - 256) * 256 + tid;    // 0..32767
    int j = gid >> 8, k = gid & 255;             // WT[j][k] = W[k][j]
    WT[gid] = f2bf(W[k * OUTn + j]);
    return;
  }
  const int b = blockIdx.x >> 5;
  const int n0 = (blockIdx.x & 31) * 64;
  __shared__ __attribute__((aligned(16))) unsigned short lds[64][130];
  #pragma unroll
  for (int c = 0; c < 32; ++c) {
    int e = tid + c * 256;
    int i = e >> 7, d = e & 127;
    lds[i][d] = f2bf(in[((size_t)(b * Nn + n0 + i)) * Dn + d]);
  }
  __syncthreads();
  #pragma unroll
  for (int c = 0; c < 4; ++c) {
    int ch = tid + c * 256;
    int d = ch >> 3, g = (ch & 7) * 8;
    ushort8 v;
    #pragma unroll
    for (int e = 0; e < 8; ++e) v[e] = lds[g + e][d];
    *(ushort8*)(inT + ((size_t)(b * Dn + d)) * Nn + n0 + g) = v;
  }
}

// ---------------- main: counted-vmcnt DMA pipeline, 4-buf, depth 3 ----------
// 1024 blocks x 256 threads (4 waves). Block = 16 rows of one batch, BK=64.
// Per iter: s_waitcnt vmcnt(10) [tile kt landed; kt+1,kt+2 (5 loads/wave each)
// IN FLIGHT] -> s_barrier -> STAGE(kt+3) -> COMPUTE(kt). Straggler slack ~2
// iterations >> HBM latency. LDS 80KB -> exactly 2 blocks/CU.
// A raw int32 in LDS, converted at frag-read (adj in {0,1}: bf16 = v*0x3F80).
// 16B-chunk XOR swizzle (chunk ^= row&7) on global source + ds_read (rule #21).
union SMem {
  struct {
    int A[4][16][64];                  // 16 KB (swizzled content, linear layout)
    unsigned short Bs[4][128][64];     // 64 KB
  } s;                                 // 80 KB -> 2 blocks/CU
  struct {
    unsigned short aggl[16][136];      // bf16 agg for GEMM2 A-frags
    float rowsum[16][4];
    float degs[16];
  } e;
};

#define STAGE(cur, kt) do {                                                    \
    {                                                                          \
      const int r_ = wv * 4 + (l >> 4);                                        \
      const int cg_ = (l & 15) ^ (r_ & 7);                                     \
      const int* gsrc_ = adjB + (size_t)r_ * Nn + (kt) * 64 + cg_ * 4;         \
      __builtin_amdgcn_global_load_lds(                                        \
          (const __attribute__((address_space(1))) void*)gsrc_,                \
          (__attribute__((address_space(3))) void*)(smc + (cur) * 4096 +       \
                                                   wv * 1024),                 \
          16, 0, 0);                                                           \
    }                                                                          \
    _Pragma("unroll")                                                          \
    for (int c_ = 0; c_ < 4; ++c_) {                                           \
      const int d_ = wv * 32 + c_ * 8 + (l >> 3);                              \
      const int cg_ = (l & 7) ^ (d_ & 7);                                      \
      const unsigned short* gsrc_ = inTb + (size_t)d_ * Nn + (kt) * 64 + cg_ * 8; \
      __builtin_amdgcn_global_load_lds(                                        \
          (const __attribute__((address_space(1))) void*)gsrc_,                \
          (__attribute__((address_space(3))) void*)(smc + 16384 +              \
                                                   (cur) * 16384 +             \
                                                   wv * 4096 + c_ * 1024),     \
          16, 0, 0);                                                           \
    }                                                                          \
  } while (0)

#define COMPUTE(cur) do {                                                      \
    const char* Abase = smc + (cur) * 4096 + lr * 256;                         \
    const char* Bbase = smc + 16384 + (cur) * 16384 + (wv * 32 + lr) * 128;    \
    _Pragma("unroll")                                                          \
    for (int kc = 0; kc < 2; ++kc) {                                           \
      const int c0_ = kc * 8 + lg * 2;                                         \
      int4v ai0 = *(const int4v*)(Abase + ((c0_ ^ swz8) * 16));                \
      int4v ai1 = *(const int4v*)(Abase + (((c0_ + 1) ^ swz8) * 16));          \
      dsum += ai0[0] + ai0[1] + ai0[2] + ai0[3] +                              \
              ai1[0] + ai1[1] + ai1[2] + ai1[3];                               \
      uint4v aw;                                                               \
      aw[0] = (unsigned)ai0[0] * 0x3F80u + (unsigned)ai0[1] * 0x3F800000u;     \
      aw[1] = (unsigned)ai0[2] * 0x3F80u + (unsigned)ai0[3] * 0x3F800000u;     \
      aw[2] = (unsigned)ai1[0] * 0x3F80u + (unsigned)ai1[1] * 0x3F800000u;     \
      aw[3] = (unsigned)ai1[2] * 0x3F80u + (unsigned)ai1[3] * 0x3F800000u;     \
      bf16x8 af = __builtin_bit_cast(bf16x8, aw);                              \
      _Pragma("unroll")                                                        \
      for (int cf = 0; cf < 2; ++cf) {                                         \
        bf16x8 bfm = *(const bf16x8*)(Bbase + (size_t)cf * 16 * 128 +          \
                                      (((kc * 4 + lg) ^ swz8) * 16));          \
        acc[cf] = __builtin_amdgcn_mfma_f32_16x16x32_bf16(af, bfm, acc[cf],    \
                                                          0, 0, 0);            \
      }                                                                        \
    }                                                                          \
  } while (0)

#define WAITBAR(N) do {                                                        \
    asm volatile("s_waitcnt vmcnt(" #N ")" ::: "memory");                      \
    __builtin_amdgcn_s_barrier();                                              \
    __builtin_amdgcn_sched_barrier(0);                                         \
  } while (0)

__global__ __launch_bounds__(256, 2) void gcn_main(
    const float* __restrict__ input_, const int* __restrict__ adj,
    const float* __restrict__ bvec, const unsigned short* __restrict__ inT,
    const unsigned short* __restrict__ WT, float* __restrict__ out) {
  __shared__ SMem sm;
  char* smc = (char*)&sm;
  const int tid = threadIdx.x;
  const int wv = tid >> 6;                       // 0..3 = col-quarter
  const int l = tid & 63, lr = l & 15, lg = (l >> 4) & 3;

  // bijective XCD swizzle: 1024 blocks (%8==0) -> XCD x gets batch x
  const int swz = (blockIdx.x & 7) * 128 + (blockIdx.x >> 3);
  const int bb = swz >> 7;
  const int row0 = (swz & 127) * 16;
  const int grow0 = bb * Nn + row0;

  const int* adjB = adj + (size_t)grow0 * Nn;
  const unsigned short* inTb = inT + (size_t)bb * Dn * Nn;

  const int swz8 = lr & 7;                       // frag-read swizzle (row&7)
  f32x4 acc[2] = {};
  int dsum = 0;

  // prologue: tiles 0,1,2 staged (15 loads/wave in flight)
  STAGE(0, 0);
  STAGE(1, 1);
  STAGE(2, 2);

  #pragma unroll 1
  for (int j = 0; j < 7; ++j) {
    const int kt = 4 * j;
    WAITBAR(10); STAGE(3, kt + 3); COMPUTE(0);
    WAITBAR(10); STAGE(0, kt + 4); COMPUTE(1);
    WAITBAR(10); STAGE(1, kt + 5); COMPUTE(2);
    WAITBAR(10); STAGE(2, kt + 6); COMPUTE(3);
  }
  // peel kt = 28..31 (last staged in-loop = tile 30; stage 31 at kt=28)
  WAITBAR(10); STAGE(3, 31); COMPUTE(0);
  WAITBAR(10); COMPUTE(1);
  WAITBAR(5);  COMPUTE(2);
  WAITBAR(0);  COMPUTE(3);

  __syncthreads();                               // close K-loop: sm re-used below

  // ---- degree (adj in {0,1}: dsum is the partial row sum; all waves equal) --
  {
    int s = dsum;
    s += __shfl_xor(s, 16);
    s += __shfl_xor(s, 32);                      // lanes lr,+16,+32,+48 summed
    if (l < 16) sm.e.degs[l] = (s == 0) ? 1.0f : (float)s;
  }
  __syncthreads();

  // ---- agg = acc/deg staged as bf16 for GEMM2 ----
  float dgi[4];
  #pragma unroll
  for (int reg = 0; reg < 4; ++reg)
    dgi[reg] = 1.0f / sm.e.degs[lg * 4 + reg];
  #pragma unroll
  for (int cf = 0; cf < 2; ++cf)
    #pragma unroll
    for (int reg = 0; reg < 4; ++reg)
      sm.e.aggl[lg * 4 + reg][wv * 32 + cf * 16 + lr] =
          f2bf(acc[cf][reg] * dgi[reg]);
  __syncthreads();

  // ---- GEMM2: [x | agg] @ W (K=256); x direct from input_, B from WT ----
  f32x4 acc2[2] = {};
  const float* xrow = input_ + (size_t)(grow0 + lr) * Dn;
  #pragma unroll
  for (int ks = 0; ks < 8; ++ks) {
    bf16x8 af;
    if (ks < 4) {
      float4v f0 = *(const float4v*)(xrow + ks * 32 + lg * 8);
      float4v f1 = *(const float4v*)(xrow + ks * 32 + lg * 8 + 4);
      ushort8 vv;
      #pragma unroll
      for (int e = 0; e < 4; ++e) { vv[e] = f2bf(f0[e]); vv[e + 4] = f2bf(f1[e]); }
      af = __builtin_bit_cast(bf16x8, vv);
    } else {
      af = *(const bf16x8*)&sm.e.aggl[lr][(ks - 4) * 32 + lg * 8];
    }
    #pragma unroll
    for (int cf = 0; cf < 2; ++cf) {
      bf16x8 bw = *(const bf16x8*)(WT + (size_t)(wv * 32 + cf * 16 + lr) * 256 +
                                   ks * 32 + lg * 8);
      acc2[cf] = __builtin_amdgcn_mfma_f32_16x16x32_bf16(af, bw, acc2[cf], 0, 0, 0);
    }
  }

  // ---- bias + sigmoid + row L2-norm + store ----
  float bcol[2];
  bcol[0] = bvec[wv * 32 + lr];
  bcol[1] = bvec[wv * 32 + 16 + lr];
  float sg[2][4];
  #pragma unroll
  for (int cf = 0; cf < 2; ++cf)
    #pragma unroll
    for (int reg = 0; reg < 4; ++reg) {
      float x = acc2[cf][reg] + bcol[cf];
      sg[cf][reg] = 1.0f / (1.0f + expf(-x));
    }
  #pragma unroll
  for (int reg = 0; reg < 4; ++reg) {
    float p = sg[0][reg] * sg[0][reg] + sg[1][reg] * sg[1][reg];
    p += __shfl_xor(p, 1);
    p += __shfl_xor(p, 2);
    p += __shfl_xor(p, 4);
    p += __shfl_xor(p, 8);
    if (lr == 0) sm.e.rowsum[lg * 4 + reg][wv] = p;
  }
  __syncthreads();
  #pragma unroll
  for (int reg = 0; reg < 4; ++reg) {
    const int row = lg * 4 + reg;
    float nrm = rsqrtf(sm.e.rowsum[row][0] + sm.e.rowsum[row][1] +
                       sm.e.rowsum[row][2] + sm.e.rowsum[row][3]);
    #pragma unroll
    for (int cf = 0; cf < 2; ++cf)
      out[(size_t)(grow0 + row) * OUTn + wv * 32 + cf * 16 + lr] =
          sg[cf][reg] * nrm;
  }
}

extern "C" void kernel_launch(void* const* d_in, const int* in_sizes, int n_in,
                              void* d_out, int out_size, void* d_ws, size_t ws_size,
                              hipStream_t stream) {
  (void)in_sizes; (void)n_in; (void)out_size; (void)ws_size;
  const float* input_ = (const float*)d_in[0];
  const int* adj = (const int*)d_in[1];
  const float* W = (const float*)d_in[2];
  const float* bvec = (const float*)d_in[3];
  float* out = (float*)d_out;

  unsigned short* inT = (unsigned short*)d_ws;                 // 4 MB
  unsigned short* WT = inT + (size_t)Bn * Dn * Nn;             // 64 KB

  hipLaunchKernelGGL(gcn_prep, dim3(384), dim3(256), 0, stream, input_, W, inT, WT);
  hipLaunchKernelGGL(gcn_main, dim3(1024), dim3(256), 0, stream,
                     input_, adj, bvec, inT, WT, out);
}

// Round 12
// 42.544 us; speedup vs baseline: 1.2838x; 1.2838x over previous
//
#include <hip/hip_runtime.h>

#define Bn 8
#define Nn 2048
#define Dn 128
#define OUTn 128

typedef __attribute__((ext_vector_type(8))) short bf16x8;     // MFMA A/B operand (8 bf16)
typedef __attribute__((ext_vector_type(8))) unsigned short ushort8;
typedef __attribute__((ext_vector_type(4))) float f32x4;      // MFMA C/D
typedef __attribute__((ext_vector_type(4))) int int4v;
typedef __attribute__((ext_vector_type(4))) unsigned int uint4v;
typedef __attribute__((ext_vector_type(4))) float float4v;

__device__ __forceinline__ unsigned short f2bf(float f) {
  unsigned int u = __builtin_bit_cast(unsigned int, f);
  u += 0x7FFFu + ((u >> 16) & 1u);   // round-to-nearest-even
  return (unsigned short)(u >> 16);
}

// ---------------- prep: transpose input + transpose W ----------------
__global__ __launch_bounds__(256) void gcn_prep(const float* __restrict__ in,
                                                const float* __restrict__ W,
                                                unsigned short* __restrict__ inT,
                                                unsigned short* __restrict__ WT) {
  const int tid = threadIdx.x;
  if (blockIdx.x >= 256) {
    int gid = (blockIdx.x - 256) * 256 + tid;    // 0..32767
    int j = gid >> 8, k = gid & 255;             // WT[j][k] = W[k][j]
    WT[gid] = f2bf(W[k * OUTn + j]);
    return;
  }
  const int b = blockIdx.x >> 5;
  const int n0 = (blockIdx.x & 31) * 64;
  __shared__ __attribute__((aligned(16))) unsigned short lds[64][130];
  #pragma unroll
  for (int c = 0; c < 32; ++c) {
    int e = tid + c * 256;
    int i = e >> 7, d = e & 127;
    lds[i][d] = f2bf(in[((size_t)(b * Nn + n0 + i)) * Dn + d]);
  }
  __syncthreads();
  #pragma unroll
  for (int c = 0; c < 4; ++c) {
    int ch = tid + c * 256;
    int d = ch >> 3, g = (ch & 7) * 8;
    ushort8 v;
    #pragma unroll
    for (int e = 0; e < 8; ++e) v[e] = lds[g + e][d];
    *(ushort8*)(inT + ((size_t)(b * Dn + d)) * Nn + n0 + g) = v;
  }
}

// ---------------- main: counted-vmcnt DMA, 3-buf, BM=64 (B traffic halved) ---
// 256 blocks x 512 threads (8 waves). Block = 64 rows of one batch, BK=64.
// DMA bytes total: A 134 MB + B 128 MB (vs 390 MB at BM=32) — the R9/R11
// counters indicate a ~20 B/cyc/CU delivery ceiling; fewer staged bytes is
// the lever. Per iter: WAITBAR(4) [tile kt landed; kt+1's 4 loads/wave in
// flight] -> STAGE(kt+2) -> COMPUTE(kt). LDS 96 KB -> 1 block/CU.
// A raw int32 in LDS, converted at frag-read (adj in {0,1}: bf16 = v*0x3F80).
// 16B-chunk XOR swizzle (chunk ^= row&7) on global source + ds_read (rule #21).
union SMem {
  struct {
    int A[3][64][64];                  // 48 KB (swizzled content, linear layout)
    unsigned short Bs[3][128][64];     // 48 KB
  } s;                                 // 96 KB -> 1 block/CU
  struct {
    unsigned short aggl[64][136];      // bf16 agg for GEMM2 A-frags
    float rowsum[64][2];
    float degs[64];
  } e;
};

#define STAGE(cur, kt) do {                                                    \
    _Pragma("unroll")                                                          \
    for (int c_ = 0; c_ < 2; ++c_) {                                           \
      const int r_ = wv * 8 + c_ * 4 + (l >> 4);                               \
      const int cg_ = (l & 15) ^ (r_ & 7);                                     \
      const int* gsrc_ = adjB + (size_t)r_ * Nn + (kt) * 64 + cg_ * 4;         \
      __builtin_amdgcn_global_load_lds(                                        \
          (const __attribute__((address_space(1))) void*)gsrc_,                \
          (__attribute__((address_space(3))) void*)(smc + (cur) * 16384 +      \
                                                   wv * 2048 + c_ * 1024),     \
          16, 0, 0);                                                           \
    }                                                                          \
    _Pragma("unroll")                                                          \
    for (int c_ = 0; c_ < 2; ++c_) {                                           \
      const int d_ = wv * 16 + c_ * 8 + (l >> 3);                              \
      const int cg_ = (l & 7) ^ (d_ & 7);                                      \
      const unsigned short* gsrc_ = inTb + (size_t)d_ * Nn + (kt) * 64 + cg_ * 8; \
      __builtin_amdgcn_global_load_lds(                                        \
          (const __attribute__((address_space(1))) void*)gsrc_,                \
          (__attribute__((address_space(3))) void*)(smc + 49152 +              \
                                                   (cur) * 16384 +             \
                                                   wv * 2048 + c_ * 1024),     \
          16, 0, 0);                                                           \
    }                                                                          \
  } while (0)

#define COMPUTE(cur) do {                                                      \
    const char* Abase = smc + (cur) * 16384 + (rg * 16 + lr) * 256;            \
    const char* Bbase = smc + 49152 + (cur) * 16384;                           \
    _Pragma("unroll")                                                          \
    for (int kc = 0; kc < 2; ++kc) {                                           \
      const int c0_ = kc * 8 + lg * 2;                                         \
      int4v ai0 = *(const int4v*)(Abase + ((c0_ ^ swz8) * 16));                \
      int4v ai1 = *(const int4v*)(Abase + (((c0_ + 1) ^ swz8) * 16));          \
      dsum += ai0[0] + ai0[1] + ai0[2] + ai0[3] +                              \
              ai1[0] + ai1[1] + ai1[2] + ai1[3];                               \
      uint4v aw;                                                               \
      aw[0] = (unsigned)ai0[0] * 0x3F80u + (unsigned)ai0[1] * 0x3F800000u;     \
      aw[1] = (unsigned)ai0[2] * 0x3F80u + (unsigned)ai0[3] * 0x3F800000u;     \
      aw[2] = (unsigned)ai1[0] * 0x3F80u + (unsigned)ai1[1] * 0x3F800000u;     \
      aw[3] = (unsigned)ai1[2] * 0x3F80u + (unsigned)ai1[3] * 0x3F800000u;     \
      bf16x8 af = __builtin_bit_cast(bf16x8, aw);                              \
      _Pragma("unroll")                                                        \
      for (int cf = 0; cf < 4; ++cf) {                                         \
        const int brow_ = ch * 64 + cf * 16 + lr;                              \
        bf16x8 bfm = *(const bf16x8*)(Bbase + (size_t)brow_ * 128 +            \
                                      (((kc * 4 + lg) ^ swz8) * 16));          \
        acc[cf] = __builtin_amdgcn_mfma_f32_16x16x32_bf16(af, bfm, acc[cf],    \
                                                          0, 0, 0);            \
      }                                                                        \
    }                                                                          \
  } while (0)

#define WAITBAR(N) do {                                                        \
    asm volatile("s_waitcnt vmcnt(" #N ")" ::: "memory");                      \
    __builtin_amdgcn_s_barrier();                                              \
    __builtin_amdgcn_sched_barrier(0);                                         \
  } while (0)

__global__ __launch_bounds__(512, 2) void gcn_main(
    const float* __restrict__ input_, const int* __restrict__ adj,
    const float* __restrict__ bvec, const unsigned short* __restrict__ inT,
    const unsigned short* __restrict__ WT, float* __restrict__ out) {
  __shared__ SMem sm;
  char* smc = (char*)&sm;
  const int tid = threadIdx.x;
  const int wv = tid >> 6;                       // 0..7
  const int l = tid & 63, lr = l & 15, lg = (l >> 4) & 3;
  const int rg = wv >> 1, ch = wv & 1;           // 16 rows x 64 cols per wave

  // bijective XCD swizzle: 256 blocks (%8==0) -> XCD x gets batch x
  const int swz = (blockIdx.x & 7) * 32 + (blockIdx.x >> 3);
  const int bb = swz >> 5;
  const int row0 = (swz & 31) * 64;
  const int grow0 = bb * Nn + row0;

  const int* adjB = adj + (size_t)grow0 * Nn;
  const unsigned short* inTb = inT + (size_t)bb * Dn * Nn;

  const int swz8 = lr & 7;                       // frag-read swizzle (row&7)
  f32x4 acc[4] = {};
  int dsum = 0;

  // prologue: tiles 0,1 staged (8 loads/wave in flight)
  STAGE(0, 0);
  STAGE(1, 1);

  #pragma unroll 1
  for (int j = 0; j < 10; ++j) {
    const int kt = 3 * j;
    WAITBAR(4); STAGE(2, kt + 2); COMPUTE(0);
    WAITBAR(4); STAGE(0, kt + 3); COMPUTE(1);
    WAITBAR(4); STAGE(1, kt + 4); COMPUTE(2);
  }
  // peel kt=30 (buf0), kt=31 (buf1); no further stages
  WAITBAR(4); COMPUTE(0);
  WAITBAR(0); COMPUTE(1);

  __syncthreads();                               // close K-loop: sm re-used below

  // ---- degree (adj in {0,1}: dsum is the partial row sum; ch-waves dup) ----
  {
    int s = dsum;
    s += __shfl_xor(s, 16);
    s += __shfl_xor(s, 32);                      // lanes lr,+16,+32,+48 summed
    if (l < 16) sm.e.degs[rg * 16 + l] = (s == 0) ? 1.0f : (float)s;
  }
  __syncthreads();

  // ---- agg = acc/deg staged as bf16 for GEMM2 ----
  float dgi[4];
  #pragma unroll
  for (int reg = 0; reg < 4; ++reg)
    dgi[reg] = 1.0f / sm.e.degs[rg * 16 + lg * 4 + reg];
  #pragma unroll
  for (int cf = 0; cf < 4; ++cf)
    #pragma unroll
    for (int reg = 0; reg < 4; ++reg)
      sm.e.aggl[rg * 16 + lg * 4 + reg][ch * 64 + cf * 16 + lr] =
          f2bf(acc[cf][reg] * dgi[reg]);
  __syncthreads();

  // ---- GEMM2: [x | agg] @ W (K=256); x direct from input_, B from WT ----
  f32x4 acc2[4] = {};
  const float* xrow = input_ + (size_t)(grow0 + rg * 16 + lr) * Dn;
  #pragma unroll
  for (int ks = 0; ks < 8; ++ks) {
    bf16x8 af;
    if (ks < 4) {
      float4v f0 = *(const float4v*)(xrow + ks * 32 + lg * 8);
      float4v f1 = *(const float4v*)(xrow + ks * 32 + lg * 8 + 4);
      ushort8 vv;
      #pragma unroll
      for (int e = 0; e < 4; ++e) { vv[e] = f2bf(f0[e]); vv[e + 4] = f2bf(f1[e]); }
      af = __builtin_bit_cast(bf16x8, vv);
    } else {
      af = *(const bf16x8*)&sm.e.aggl[rg * 16 + lr][(ks - 4) * 32 + lg * 8];
    }
    #pragma unroll
    for (int cf = 0; cf < 4; ++cf) {
      bf16x8 bw = *(const bf16x8*)(WT + (size_t)(ch * 64 + cf * 16 + lr) * 256 +
                                   ks * 32 + lg * 8);
      acc2[cf] = __builtin_amdgcn_mfma_f32_16x16x32_bf16(af, bw, acc2[cf], 0, 0, 0);
    }
  }

  // ---- bias + sigmoid + row L2-norm + store ----
  float bcol[4];
  #pragma unroll
  for (int cf = 0; cf < 4; ++cf) bcol[cf] = bvec[ch * 64 + cf * 16 + lr];
  float sg[4][4];
  #pragma unroll
  for (int cf = 0; cf < 4; ++cf)
    #pragma unroll
    for (int reg = 0; reg < 4; ++reg) {
      float x = acc2[cf][reg] + bcol[cf];
      sg[cf][reg] = 1.0f / (1.0f + expf(-x));
    }
  #pragma unroll
  for (int reg = 0; reg < 4; ++reg) {
    float p = 0.f;
    #pragma unroll
    for (int cf = 0; cf < 4; ++cf) p += sg[cf][reg] * sg[cf][reg];
    p += __shfl_xor(p, 1);
    p += __shfl_xor(p, 2);
    p += __shfl_xor(p, 4);
    p += __shfl_xor(p, 8);
    if (lr == 0) sm.e.rowsum[rg * 16 + lg * 4 + reg][ch] = p;
  }
  __syncthreads();
  #pragma unroll
  for (int reg = 0; reg < 4; ++reg) {
    const int row = rg * 16 + lg * 4 + reg;
    float nrm = rsqrtf(sm.e.rowsum[row][0] + sm.e.rowsum[row][1]);
    #pragma unroll
    for (int cf = 0; cf < 4; ++cf)
      out[(size_t)(grow0 + row) * OUTn + ch * 64 + cf * 16 + lr] =
          sg[cf][reg] * nrm;
  }
}

extern "C" void kernel_launch(void* const* d_in, const int* in_sizes, int n_in,
                              void* d_out, int out_size, void* d_ws, size_t ws_size,
                              hipStream_t stream) {
  (void)in_sizes; (void)n_in; (void)out_size; (void)ws_size;
  const float* input_ = (const float*)d_in[0];
  const int* adj = (const int*)d_in[1];
  const float* W = (const float*)d_in[2];
  const float* bvec = (const float*)d_in[3];
  float* out = (float*)d_out;

  unsigned short* inT = (unsigned short*)d_ws;                 // 4 MB
  unsigned short* WT = inT + (size_t)Bn * Dn * Nn;             // 64 KB

  hipLaunchKernelGGL(gcn_prep, dim3(384), dim3(256), 0, stream, input_, W, inT, WT);
  hipLaunchKernelGGL(gcn_main, dim3(256), dim3(512), 0, stream,
                     input_, adj, bvec, inT, WT, out);
}